// Round 6
// baseline (241.528 us; speedup 1.0000x reference)
//
#include <hip/hip_runtime.h>
#include <cstdint>

#define DIM   768
#define HEADS 12
#define HDIM  64
#define BATCH 4
#define SEQ   2048
#define MROWS (BATCH*SEQ)   // 8192

typedef __bf16 bf16;
typedef __bf16 bf16x4_t __attribute__((ext_vector_type(4)));
typedef __bf16 bf16x8_t __attribute__((ext_vector_type(8)));
typedef float  f32x4_t  __attribute__((ext_vector_type(4)));
typedef short  short4_t __attribute__((ext_vector_type(4)));

// K=16 bf16 MFMA: A/B = 4 bf16 (2 VGPR), C/D = 4 f32.
__device__ __forceinline__ f32x4_t mfma16x16x16bf16(bf16x4_t a, bf16x4_t b, f32x4_t c) {
#if __has_builtin(__builtin_amdgcn_mfma_f32_16x16x16_bf16)
    return __builtin_amdgcn_mfma_f32_16x16x16_bf16(a, b, c, 0, 0, 0);
#elif __has_builtin(__builtin_amdgcn_mfma_f32_16x16x16bf16_1k)
    union U { bf16x4_t h; short4_t s; };
    U ua, ub; ua.h = a; ub.h = b;
    return __builtin_amdgcn_mfma_f32_16x16x16bf16_1k(ua.s, ub.s, c, 0, 0, 0);
#else
    asm("v_mfma_f32_16x16x16_bf16 %0, %1, %2, %0" : "+v"(c) : "v"(a), "v"(b));
    return c;
#endif
}

// ---------------- fp32 -> bf16 casts ----------------
__global__ void cast_bf16_kernel(const float* __restrict__ src, bf16* __restrict__ dst, int n4) {
    int i = blockIdx.x * blockDim.x + threadIdx.x;
    if (i >= n4) return;
    const float4 v = reinterpret_cast<const float4*>(src)[i];
    bf16x4_t o;
    o[0] = (bf16)v.x; o[1] = (bf16)v.y; o[2] = (bf16)v.z; o[3] = (bf16)v.w;
    reinterpret_cast<bf16x4_t*>(dst)[i] = o;
}

__global__ void cast_w4_kernel(const float* __restrict__ s0, const float* __restrict__ s1,
                               const float* __restrict__ s2, const float* __restrict__ s3,
                               bf16* __restrict__ d0, bf16* __restrict__ d1,
                               bf16* __restrict__ d2, bf16* __restrict__ d3, int n4) {
    int i = blockIdx.x * blockDim.x + threadIdx.x;
    if (i >= n4) return;
    int y = blockIdx.y;
    const float* src = (y == 0) ? s0 : (y == 1) ? s1 : (y == 2) ? s2 : s3;
    bf16* dst        = (y == 0) ? d0 : (y == 1) ? d1 : (y == 2) ? d2 : d3;
    const float4 v = reinterpret_cast<const float4*>(src)[i];
    bf16x4_t o;
    o[0] = (bf16)v.x; o[1] = (bf16)v.y; o[2] = (bf16)v.z; o[3] = (bf16)v.w;
    reinterpret_cast<bf16x4_t*>(dst)[i] = o;
}

// async global->LDS, 16B per lane. LDS dest is wave-uniform base + lane*16.
__device__ __forceinline__ void gload_lds16(const bf16* g, bf16* l) {
    __builtin_amdgcn_global_load_lds((const __attribute__((address_space(1))) void*)g,
                                     (__attribute__((address_space(3))) void*)l, 16, 0, 0);
}

// ---------------- Q/K projection GEMM ----------------
// z=0 -> Q [B,H,N,64] (pre-scaled by log2(e)/8), z=1 -> K [B,H,N,64]
__global__ __launch_bounds__(256, 2) void qkv_gemm(
        const bf16* __restrict__ X,
        const bf16* __restrict__ Wq, const bf16* __restrict__ Wk,
        bf16* __restrict__ Q, bf16* __restrict__ Kd)
{
    __shared__ bf16 As[128*32];
    __shared__ bf16 Bs[128*32];
    const int tid  = threadIdx.x;
    const int z    = blockIdx.z;
    const bf16* W  = (z == 0) ? Wq : Wk;
    const int n0   = blockIdx.x * 128;
    const int m0   = blockIdx.y * 128;
    const int lane = tid & 63;
    const int w    = tid >> 6;
    const int wm   = (w & 1) * 64, wn = (w >> 1) * 64;
    const int lr   = lane & 15, quad = lane >> 4;

    f32x4_t acc[4][4] = {};

    for (int kk = 0; kk < DIM; kk += 32) {
        #pragma unroll
        for (int i = 0; i < 2; ++i) {
            int c = tid + i * 256;
            int row = c >> 2, ko = (c & 3) * 8;
            gload_lds16(X + (size_t)(m0 + row) * DIM + kk + ko, &As[row * 32 + ko]);
            gload_lds16(W + (size_t)(n0 + row) * DIM + kk + ko, &Bs[row * 32 + ko]);
        }
        __syncthreads();
        bf16x8_t af[4], bfr[4];
        #pragma unroll
        for (int i = 0; i < 4; ++i)
            af[i] = *reinterpret_cast<const bf16x8_t*>(&As[(wm + i * 16 + lr) * 32 + quad * 8]);
        #pragma unroll
        for (int j = 0; j < 4; ++j)
            bfr[j] = *reinterpret_cast<const bf16x8_t*>(&Bs[(wn + j * 16 + lr) * 32 + quad * 8]);
        #pragma unroll
        for (int i = 0; i < 4; ++i)
            #pragma unroll
            for (int j = 0; j < 4; ++j)
                acc[i][j] = __builtin_amdgcn_mfma_f32_16x16x32_bf16(af[i], bfr[j], acc[i][j], 0, 0, 0);
        __syncthreads();
    }

    const float sc = (z == 0) ? 0.18033688011112042f : 1.0f;  // log2(e)/8 folded into Q
    bf16* dst = (z == 0) ? Q : Kd;
    #pragma unroll
    for (int i = 0; i < 4; ++i) {
        int mbase = m0 + wm + i * 16 + quad * 4;
        #pragma unroll
        for (int j = 0; j < 4; ++j) {
            int n = n0 + wn + j * 16 + lr;
            int h = n >> 6, d = n & 63;
            #pragma unroll
            for (int r = 0; r < 4; ++r) {
                int m = mbase + r;
                int b = m >> 11, row = m & 2047;
                dst[(((size_t)b * HEADS + h) * SEQ + row) * HDIM + d] = (bf16)(acc[i][j][r] * sc);
            }
        }
    }
}

// ---------------- V^T GEMM: Vt[768][8192] = Wv · X^T (row-major, coalesced) ----------------
__global__ __launch_bounds__(256, 2) void vt_gemm(
        const bf16* __restrict__ Wv,   // [768,768] "A" (M rows = d_full)
        const bf16* __restrict__ X,    // [8192,768] "B" (N rows = sample)
        bf16* __restrict__ Vt)         // [768, 8192]
{
    __shared__ bf16 As[128*32];
    __shared__ bf16 Bs[128*32];
    const int tid  = threadIdx.x;
    const int n0   = blockIdx.x * 128;     // sample
    const int m0   = blockIdx.y * 128;     // d_full
    const int lane = tid & 63;
    const int w    = tid >> 6;
    const int wm   = (w & 1) * 64, wn = (w >> 1) * 64;
    const int lr   = lane & 15, quad = lane >> 4;

    f32x4_t acc[4][4] = {};

    for (int kk = 0; kk < DIM; kk += 32) {
        #pragma unroll
        for (int i = 0; i < 2; ++i) {
            int c = tid + i * 256;
            int row = c >> 2, ko = (c & 3) * 8;
            gload_lds16(Wv + (size_t)(m0 + row) * DIM + kk + ko, &As[row * 32 + ko]);
            gload_lds16(X  + (size_t)(n0 + row) * DIM + kk + ko, &Bs[row * 32 + ko]);
        }
        __syncthreads();
        bf16x8_t af[4], bfr[4];
        #pragma unroll
        for (int i = 0; i < 4; ++i)
            af[i] = *reinterpret_cast<const bf16x8_t*>(&As[(wm + i * 16 + lr) * 32 + quad * 8]);
        #pragma unroll
        for (int j = 0; j < 4; ++j)
            bfr[j] = *reinterpret_cast<const bf16x8_t*>(&Bs[(wn + j * 16 + lr) * 32 + quad * 8]);
        #pragma unroll
        for (int i = 0; i < 4; ++i)
            #pragma unroll
            for (int j = 0; j < 4; ++j)
                acc[i][j] = __builtin_amdgcn_mfma_f32_16x16x32_bf16(af[i], bfr[j], acc[i][j], 0, 0, 0);
        __syncthreads();
    }

    #pragma unroll
    for (int i = 0; i < 4; ++i) {
        int mbase = m0 + wm + i * 16 + quad * 4;
        #pragma unroll
        for (int j = 0; j < 4; ++j) {
            int n = n0 + wn + j * 16 + lr;
            #pragma unroll
            for (int r = 0; r < 4; ++r)
                Vt[(size_t)(mbase + r) * MROWS + n] = (bf16)acc[i][j][r];
        }
    }
}

// ---------------- output projection GEMM (+bias, fp32 out) ----------------
__global__ __launch_bounds__(256, 2) void out_gemm(
        const bf16* __restrict__ A,
        const bf16* __restrict__ W,
        const float* __restrict__ bias,
        float* __restrict__ out)
{
    __shared__ bf16 As[128*32];
    __shared__ bf16 Bs[128*32];
    const int tid  = threadIdx.x;
    const int n0   = blockIdx.x * 128;
    const int m0   = blockIdx.y * 128;
    const int lane = tid & 63;
    const int w    = tid >> 6;
    const int wm   = (w & 1) * 64, wn = (w >> 1) * 64;
    const int lr   = lane & 15, quad = lane >> 4;

    f32x4_t acc[4][4] = {};

    for (int kk = 0; kk < DIM; kk += 32) {
        #pragma unroll
        for (int i = 0; i < 2; ++i) {
            int c = tid + i * 256;
            int row = c >> 2, ko = (c & 3) * 8;
            gload_lds16(A + (size_t)(m0 + row) * DIM + kk + ko, &As[row * 32 + ko]);
            gload_lds16(W + (size_t)(n0 + row) * DIM + kk + ko, &Bs[row * 32 + ko]);
        }
        __syncthreads();
        bf16x8_t af[4], bfr[4];
        #pragma unroll
        for (int i = 0; i < 4; ++i)
            af[i] = *reinterpret_cast<const bf16x8_t*>(&As[(wm + i * 16 + lr) * 32 + quad * 8]);
        #pragma unroll
        for (int j = 0; j < 4; ++j)
            bfr[j] = *reinterpret_cast<const bf16x8_t*>(&Bs[(wn + j * 16 + lr) * 32 + quad * 8]);
        #pragma unroll
        for (int i = 0; i < 4; ++i)
            #pragma unroll
            for (int j = 0; j < 4; ++j)
                acc[i][j] = __builtin_amdgcn_mfma_f32_16x16x32_bf16(af[i], bfr[j], acc[i][j], 0, 0, 0);
        __syncthreads();
    }

    #pragma unroll
    for (int i = 0; i < 4; ++i) {
        int mbase = m0 + wm + i * 16 + quad * 4;
        #pragma unroll
        for (int j = 0; j < 4; ++j) {
            int n = n0 + wn + j * 16 + lr;
            float bv = bias[n];
            #pragma unroll
            for (int r = 0; r < 4; ++r) {
                int m = mbase + r;
                out[(size_t)m * DIM + n] = acc[i][j][r] + bv;
            }
        }
    }
}

// ---------------- flash attention v5 ----------------
// Q-tile 64 (each of 4 waves owns 16 queries) -> 1536 blocks -> 5 blocks/CU
// (LDS-limited) for latency hiding. K-tile 64 double-buffered, swizzled,
// register-P path, MFMA row-sums. Q pre-scaled by log2(e)/8.
__global__ __launch_bounds__(256, 5) void attn_kernel(
        const bf16* __restrict__ Q, const bf16* __restrict__ Kd,
        const bf16* __restrict__ Vt, bf16* __restrict__ Ab)
{
    __shared__ __align__(16) bf16 KV[2][2][64*64];   // [buf][K|V][row*64] swizzled

    const int tid  = threadIdx.x;
    const int bh   = blockIdx.y;
    const int b    = bh / HEADS, h = bh % HEADS;
    const int q0   = blockIdx.x * 64;
    const int lane = tid & 63, w = tid >> 6;
    const int lr   = lane & 15, quad = lane >> 4;
    const int wq   = w * 16;

    const size_t qkbase = (size_t)bh * SEQ * HDIM;
    const size_t vbase  = (size_t)h * HDIM * MROWS + (size_t)b * SEQ;

    // per-lane staging coords (loop-invariant)
    const int src_row = tid >> 3, src_ch = tid & 7;
    const int src_gch = src_ch ^ (src_row & 7);
    const int src_row2 = (tid + 256) >> 3, src_ch2 = tid & 7;   // c+256: row+32, same ch
    const int src_gch2 = src_ch2 ^ (src_row2 & 7);

    // stage Q (64x64, swizzled) into KV[1][0] (8 KB)
    {
        bf16* Qst = &KV[1][0][0];
        gload_lds16(Q + qkbase + (size_t)(q0 + src_row) * HDIM + src_gch * 8,
                    &Qst[src_row * 64 + src_ch * 8]);
        gload_lds16(Q + qkbase + (size_t)(q0 + src_row2) * HDIM + src_gch2 * 8,
                    &Qst[src_row2 * 64 + src_ch2 * 8]);
    }

    // staging pointers, advanced by constant stride per tile
    const bf16* kp1 = Kd + qkbase + (size_t)src_row  * HDIM + src_gch  * 8;
    const bf16* kp2 = Kd + qkbase + (size_t)src_row2 * HDIM + src_gch2 * 8;
    const bf16* vp1 = Vt + vbase  + (size_t)src_row  * MROWS + src_gch  * 8;
    const bf16* vp2 = Vt + vbase  + (size_t)src_row2 * MROWS + src_gch2 * 8;
    bf16* kl1 = &KV[0][0][src_row  * 64 + src_ch  * 8];
    bf16* kl2 = &KV[0][0][src_row2 * 64 + src_ch2 * 8];
    bf16* vl1 = &KV[0][1][src_row  * 64 + src_ch  * 8];
    bf16* vl2 = &KV[0][1][src_row2 * 64 + src_ch2 * 8];
    const ptrdiff_t kstep = 64 * HDIM, vstep = 64;
    const ptrdiff_t lstep = 2 * 64 * 64;   // buf stride in elems

    // tile 0 -> buf 0
    gload_lds16(kp1, kl1); gload_lds16(kp2, kl2);
    gload_lds16(vp1, vl1); gload_lds16(vp2, vl2);
    __syncthreads();

    // Q B-operand fragments -> registers (8 VGPRs)
    bf16x8_t qf[2];
    {
        const bf16* Qst = &KV[1][0][0];
        int row = wq + lr;
        #pragma unroll
        for (int ks = 0; ks < 2; ++ks) {
            int ch = (ks * 4 + quad) ^ (row & 7);
            qf[ks] = *reinterpret_cast<const bf16x8_t*>(&Qst[row * 64 + ch * 8]);
        }
    }
    __syncthreads();   // all waves read Q; KV[1] becomes buf 1

    f32x4_t oacc[4] = {};
    f32x4_t rsacc = {};
    bf16x4_t ones4;
    ones4[0] = (bf16)1.0f; ones4[1] = (bf16)1.0f; ones4[2] = (bf16)1.0f; ones4[3] = (bf16)1.0f;

    for (int it = 0; it < SEQ / 64; ++it) {
        const int buf = it & 1;
        if (it + 1 < SEQ / 64) {
            const ptrdiff_t g = (ptrdiff_t)(it + 1);
            const ptrdiff_t l = (buf ^ 1) ? lstep : 0;
            gload_lds16(kp1 + g * kstep, kl1 + l); gload_lds16(kp2 + g * kstep, kl2 + l);
            gload_lds16(vp1 + g * vstep, vl1 + l); gload_lds16(vp2 + g * vstep, vl2 + l);
        }

        const bf16* Ks = &KV[buf][0][0];
        const bf16* Vs = &KV[buf][1][0];

        // S^T: A = K rows (M=key), B = Q rows (N=query), 16x16x32
        f32x4_t sacc[4] = {};
        #pragma unroll
        for (int ks = 0; ks < 2; ++ks) {
            bf16x8_t af[4];
            #pragma unroll
            for (int kt = 0; kt < 4; ++kt) {
                int row = kt * 16 + lr;
                int ch = (ks * 4 + quad) ^ (row & 7);
                af[kt] = *reinterpret_cast<const bf16x8_t*>(&Ks[row * 64 + ch * 8]);
            }
            #pragma unroll
            for (int kt = 0; kt < 4; ++kt)
                sacc[kt] = __builtin_amdgcn_mfma_f32_16x16x32_bf16(
                    af[kt], qf[ks], sacc[kt], 0, 0, 0);
        }

        // p = exp2(s); pk is already the K=16 A-operand frag.
        #pragma unroll
        for (int kt = 0; kt < 4; ++kt) {
            bf16x4_t bv[4];
            #pragma unroll
            for (int dt = 0; dt < 4; ++dt) {
                int row = dt * 16 + lr;
                int ch = (2 * kt + (quad >> 1)) ^ (row & 7);
                bv[dt] = *reinterpret_cast<const bf16x4_t*>(&Vs[row * 64 + ch * 8 + (quad & 1) * 4]);
            }
            bf16x4_t pk;
            #pragma unroll
            for (int r = 0; r < 4; ++r)
                pk[r] = (bf16)__builtin_amdgcn_exp2f(sacc[kt][r]);
            rsacc = mfma16x16x16bf16(pk, ones4, rsacc);   // row sums
            #pragma unroll
            for (int dt = 0; dt < 4; ++dt)
                oacc[dt] = mfma16x16x16bf16(pk, bv[dt], oacc[dt]);
        }
        __syncthreads();   // protects buf for it+2 staging
    }

    // rsacc lane mapping == oacc mapping (query = quad*4+r) -> no shuffles
    float inv[4];
    #pragma unroll
    for (int r = 0; r < 4; ++r)
        inv[r] = 1.0f / rsacc[r];
    #pragma unroll
    for (int dt = 0; dt < 4; ++dt) {
        #pragma unroll
        for (int r = 0; r < 4; ++r) {
            int q = q0 + wq + quad * 4 + r;
            Ab[((size_t)b * SEQ + q) * DIM + h * HDIM + dt * 16 + lr] =
                (bf16)(oacc[dt][r] * inv[r]);
        }
    }
}

extern "C" void kernel_launch(void* const* d_in, const int* in_sizes, int n_in,
                              void* d_out, int out_size, void* d_ws, size_t ws_size,
                              hipStream_t stream) {
    (void)in_sizes; (void)n_in; (void)out_size; (void)ws_size;
    const float* x  = (const float*)d_in[0];
    const float* Wq = (const float*)d_in[1];
    const float* Wk = (const float*)d_in[2];
    const float* Wv = (const float*)d_in[3];
    const float* Wp = (const float*)d_in[4];
    const float* bp = (const float*)d_in[5];
    float* out = (float*)d_out;

    char* ws = (char*)d_ws;
    size_t off = 0;
    auto alloc = [&](size_t bytes) {
        void* p = ws + off;
        off += (bytes + 255) & ~(size_t)255;
        return p;
    };
    const size_t big = (size_t)MROWS * DIM * sizeof(bf16);
    const size_t wsz = (size_t)DIM * DIM * sizeof(bf16);
    bf16* Xb  = (bf16*)alloc(big);
    bf16* Qb  = (bf16*)alloc(big);
    bf16* Kb  = (bf16*)alloc(big);
    bf16* Vtb = (bf16*)alloc(big);
    bf16* Wqb = (bf16*)alloc(wsz);
    bf16* Wkb = (bf16*)alloc(wsz);
    bf16* Wvb = (bf16*)alloc(wsz);
    bf16* Wpb = (bf16*)alloc(wsz);
    bf16* Ab  = Xb;   // Xb dead after projections

    const int x4 = MROWS * DIM / 4;
    cast_bf16_kernel<<<(x4 + 255) / 256, 256, 0, stream>>>(x, Xb, x4);
    const int w4 = DIM * DIM / 4;
    cast_w4_kernel<<<dim3((w4 + 255) / 256, 4), 256, 0, stream>>>(
        Wq, Wk, Wv, Wp, Wqb, Wkb, Wvb, Wpb, w4);

    qkv_gemm<<<dim3(DIM / 128, MROWS / 128, 2), 256, 0, stream>>>(Xb, Wqb, Wkb, Qb, Kb);
    vt_gemm<<<dim3(MROWS / 128, DIM / 128), 256, 0, stream>>>(Wvb, Xb, Vtb);

    attn_kernel<<<dim3(SEQ / 64, BATCH * HEADS), 256, 0, stream>>>(Qb, Kb, Vtb, Ab);

    out_gemm<<<dim3(DIM / 128, MROWS / 128), 256, 0, stream>>>(Ab, Wpb, bp, out);
}

// Round 7
// 227.584 us; speedup vs baseline: 1.0613x; 1.0613x over previous
//
#include <hip/hip_runtime.h>
#include <cstdint>

#define DIM   768
#define HEADS 12
#define HDIM  64
#define BATCH 4
#define SEQ   2048
#define MROWS (BATCH*SEQ)   // 8192

typedef __bf16 bf16;
typedef __bf16 bf16x4_t __attribute__((ext_vector_type(4)));
typedef __bf16 bf16x8_t __attribute__((ext_vector_type(8)));
typedef float  f32x4_t  __attribute__((ext_vector_type(4)));
typedef short  short4_t __attribute__((ext_vector_type(4)));

// K=16 bf16 MFMA: A/B = 4 bf16 (2 VGPR), C/D = 4 f32.
__device__ __forceinline__ f32x4_t mfma16x16x16bf16(bf16x4_t a, bf16x4_t b, f32x4_t c) {
#if __has_builtin(__builtin_amdgcn_mfma_f32_16x16x16_bf16)
    return __builtin_amdgcn_mfma_f32_16x16x16_bf16(a, b, c, 0, 0, 0);
#elif __has_builtin(__builtin_amdgcn_mfma_f32_16x16x16bf16_1k)
    union U { bf16x4_t h; short4_t s; };
    U ua, ub; ua.h = a; ub.h = b;
    return __builtin_amdgcn_mfma_f32_16x16x16bf16_1k(ua.s, ub.s, c, 0, 0, 0);
#else
    asm("v_mfma_f32_16x16x16_bf16 %0, %1, %2, %0" : "+v"(c) : "v"(a), "v"(b));
    return c;
#endif
}

// ---------------- fp32 -> bf16 casts ----------------
__global__ void cast_bf16_kernel(const float* __restrict__ src, bf16* __restrict__ dst, int n4) {
    int i = blockIdx.x * blockDim.x + threadIdx.x;
    if (i >= n4) return;
    const float4 v = reinterpret_cast<const float4*>(src)[i];
    bf16x4_t o;
    o[0] = (bf16)v.x; o[1] = (bf16)v.y; o[2] = (bf16)v.z; o[3] = (bf16)v.w;
    reinterpret_cast<bf16x4_t*>(dst)[i] = o;
}

__global__ void cast_w4_kernel(const float* __restrict__ s0, const float* __restrict__ s1,
                               const float* __restrict__ s2, const float* __restrict__ s3,
                               bf16* __restrict__ d0, bf16* __restrict__ d1,
                               bf16* __restrict__ d2, bf16* __restrict__ d3, int n4) {
    int i = blockIdx.x * blockDim.x + threadIdx.x;
    if (i >= n4) return;
    int y = blockIdx.y;
    const float* src = (y == 0) ? s0 : (y == 1) ? s1 : (y == 2) ? s2 : s3;
    bf16* dst        = (y == 0) ? d0 : (y == 1) ? d1 : (y == 2) ? d2 : d3;
    const float4 v = reinterpret_cast<const float4*>(src)[i];
    bf16x4_t o;
    o[0] = (bf16)v.x; o[1] = (bf16)v.y; o[2] = (bf16)v.z; o[3] = (bf16)v.w;
    reinterpret_cast<bf16x4_t*>(dst)[i] = o;
}

// async global->LDS, 16B per lane. LDS dest is wave-uniform base + lane*16.
__device__ __forceinline__ void gload_lds16(const bf16* g, bf16* l) {
    __builtin_amdgcn_global_load_lds((const __attribute__((address_space(1))) void*)g,
                                     (__attribute__((address_space(3))) void*)l, 16, 0, 0);
}

// ---------------- merged projection GEMM ----------------
// z=0 -> Q [B,H,N,64] (pre-scaled by log2(e)/8): A=X(m=sample), B=Wq(n=dfull)
// z=1 -> K [B,H,N,64]:                            A=X,          B=Wk
// z=2 -> Vt [768][8192]:                          A=Wv(m=dfull), B=X(n=sample)
// grid (6, 64, 3): z=2 swaps blockIdx roles so m0<768, n0<8192.
__global__ __launch_bounds__(256, 3) void qkvv_gemm(
        const bf16* __restrict__ X,
        const bf16* __restrict__ Wq, const bf16* __restrict__ Wk, const bf16* __restrict__ Wv,
        bf16* __restrict__ Q, bf16* __restrict__ Kd, bf16* __restrict__ Vt)
{
    __shared__ bf16 As[128*32];
    __shared__ bf16 Bs[128*32];
    const int tid  = threadIdx.x;
    const int z    = blockIdx.z;
    const bf16* Ap; const bf16* Bp;
    int m0, n0;
    if (z == 2) { Ap = Wv; Bp = X;               m0 = blockIdx.x * 128; n0 = blockIdx.y * 128; }
    else        { Ap = X;  Bp = (z ? Wk : Wq);   m0 = blockIdx.y * 128; n0 = blockIdx.x * 128; }
    const int lane = tid & 63;
    const int w    = tid >> 6;
    const int wm   = (w & 1) * 64, wn = (w >> 1) * 64;
    const int lr   = lane & 15, quad = lane >> 4;

    f32x4_t acc[4][4] = {};

    for (int kk = 0; kk < DIM; kk += 32) {
        #pragma unroll
        for (int i = 0; i < 2; ++i) {
            int c = tid + i * 256;
            int row = c >> 2, ko = (c & 3) * 8;
            gload_lds16(Ap + (size_t)(m0 + row) * DIM + kk + ko, &As[row * 32 + ko]);
            gload_lds16(Bp + (size_t)(n0 + row) * DIM + kk + ko, &Bs[row * 32 + ko]);
        }
        __syncthreads();
        bf16x8_t af[4], bfr[4];
        #pragma unroll
        for (int i = 0; i < 4; ++i)
            af[i] = *reinterpret_cast<const bf16x8_t*>(&As[(wm + i * 16 + lr) * 32 + quad * 8]);
        #pragma unroll
        for (int j = 0; j < 4; ++j)
            bfr[j] = *reinterpret_cast<const bf16x8_t*>(&Bs[(wn + j * 16 + lr) * 32 + quad * 8]);
        #pragma unroll
        for (int i = 0; i < 4; ++i)
            #pragma unroll
            for (int j = 0; j < 4; ++j)
                acc[i][j] = __builtin_amdgcn_mfma_f32_16x16x32_bf16(af[i], bfr[j], acc[i][j], 0, 0, 0);
        __syncthreads();
    }

    if (z == 2) {
        // Vt[m(dfull)][n(sample)] — n = ..+lr is coalesced
        #pragma unroll
        for (int i = 0; i < 4; ++i) {
            int mbase = m0 + wm + i * 16 + quad * 4;
            #pragma unroll
            for (int j = 0; j < 4; ++j) {
                int n = n0 + wn + j * 16 + lr;
                #pragma unroll
                for (int r = 0; r < 4; ++r)
                    Vt[(size_t)(mbase + r) * MROWS + n] = (bf16)acc[i][j][r];
            }
        }
    } else {
        const float sc = (z == 0) ? 0.18033688011112042f : 1.0f;  // log2(e)/8 folded into Q
        bf16* dst = (z == 0) ? Q : Kd;
        #pragma unroll
        for (int i = 0; i < 4; ++i) {
            int mbase = m0 + wm + i * 16 + quad * 4;
            #pragma unroll
            for (int j = 0; j < 4; ++j) {
                int n = n0 + wn + j * 16 + lr;
                int h = n >> 6, d = n & 63;
                #pragma unroll
                for (int r = 0; r < 4; ++r) {
                    int m = mbase + r;
                    int b = m >> 11, row = m & 2047;
                    dst[(((size_t)b * HEADS + h) * SEQ + row) * HDIM + d] = (bf16)(acc[i][j][r] * sc);
                }
            }
        }
    }
}

// ---------------- output projection GEMM (+bias, fp32 out) ----------------
// 64x128 tile -> grid (6, 128) = 768 blocks = 3/CU, perfectly balanced.
__global__ __launch_bounds__(256, 4) void out_gemm(
        const bf16* __restrict__ A,       // [8192,768]
        const bf16* __restrict__ W,       // [768,768]
        const float* __restrict__ bias,
        float* __restrict__ out)          // [8192,768] f32
{
    __shared__ bf16 As[64*32];
    __shared__ bf16 Bs[128*32];
    const int tid  = threadIdx.x;
    const int n0   = blockIdx.x * 128;
    const int m0   = blockIdx.y * 64;
    const int lane = tid & 63;
    const int w    = tid >> 6;
    const int wm   = (w & 1) * 32, wn = (w >> 1) * 64;
    const int lr   = lane & 15, quad = lane >> 4;

    f32x4_t acc[2][4] = {};

    for (int kk = 0; kk < DIM; kk += 32) {
        {
            int row = tid >> 2, ko = (tid & 3) * 8;          // 256 threads cover As 64x32
            gload_lds16(A + (size_t)(m0 + row) * DIM + kk + ko, &As[row * 32 + ko]);
        }
        #pragma unroll
        for (int i = 0; i < 2; ++i) {                        // 512 covers Bs 128x32
            int c = tid + i * 256;
            int row = c >> 2, ko = (c & 3) * 8;
            gload_lds16(W + (size_t)(n0 + row) * DIM + kk + ko, &Bs[row * 32 + ko]);
        }
        __syncthreads();
        bf16x8_t af[2], bfr[4];
        #pragma unroll
        for (int i = 0; i < 2; ++i)
            af[i] = *reinterpret_cast<const bf16x8_t*>(&As[(wm + i * 16 + lr) * 32 + quad * 8]);
        #pragma unroll
        for (int j = 0; j < 4; ++j)
            bfr[j] = *reinterpret_cast<const bf16x8_t*>(&Bs[(wn + j * 16 + lr) * 32 + quad * 8]);
        #pragma unroll
        for (int i = 0; i < 2; ++i)
            #pragma unroll
            for (int j = 0; j < 4; ++j)
                acc[i][j] = __builtin_amdgcn_mfma_f32_16x16x32_bf16(af[i], bfr[j], acc[i][j], 0, 0, 0);
        __syncthreads();
    }

    #pragma unroll
    for (int i = 0; i < 2; ++i) {
        int mbase = m0 + wm + i * 16 + quad * 4;
        #pragma unroll
        for (int j = 0; j < 4; ++j) {
            int n = n0 + wn + j * 16 + lr;
            float bv = bias[n];
            #pragma unroll
            for (int r = 0; r < 4; ++r) {
                int m = mbase + r;
                out[(size_t)m * DIM + n] = acc[i][j][r] + bv;
            }
        }
    }
}

// ---------------- flash attention (round-5 v4, known-good) ----------------
// Q-tile 128 (wave owns 32 queries), K-tile 64 double-buffered, swizzled,
// register-P path, MFMA row-sums. Q pre-scaled by log2(e)/8.
__global__ __launch_bounds__(256, 4) void attn_kernel(
        const bf16* __restrict__ Q, const bf16* __restrict__ Kd,
        const bf16* __restrict__ Vt, bf16* __restrict__ Ab)
{
    __shared__ __align__(16) bf16 KV[2][2][64*64];   // [buf][K|V][row*64] swizzled

    const int tid  = threadIdx.x;
    const int bh   = blockIdx.y;
    const int b    = bh / HEADS, h = bh % HEADS;
    const int q0   = blockIdx.x * 128;
    const int lane = tid & 63, w = tid >> 6;
    const int lr   = lane & 15, quad = lane >> 4;
    const int wq   = w * 32;

    const size_t qkbase = (size_t)bh * SEQ * HDIM;
    const size_t vbase  = (size_t)h * HDIM * MROWS + (size_t)b * SEQ;

    const int src_row = tid >> 3, src_ch = tid & 7;
    const int src_gch = src_ch ^ (src_row & 7);
    const int src_row2 = (tid + 256) >> 3, src_ch2 = tid & 7;
    const int src_gch2 = src_ch2 ^ (src_row2 & 7);

    // stage Q (128x64, swizzled) into KV[1] (16 KB)
    {
        bf16* Qst = &KV[1][0][0];
        #pragma unroll
        for (int i = 0; i < 4; ++i) {
            int c = tid + i * 256;
            int row = c >> 3, ch = c & 7;
            int gch = ch ^ (row & 7);
            gload_lds16(Q + qkbase + (size_t)(q0 + row) * HDIM + gch * 8, &Qst[row * 64 + ch * 8]);
        }
    }

    const bf16* kp1 = Kd + qkbase + (size_t)src_row  * HDIM + src_gch  * 8;
    const bf16* kp2 = Kd + qkbase + (size_t)src_row2 * HDIM + src_gch2 * 8;
    const bf16* vp1 = Vt + vbase  + (size_t)src_row  * MROWS + src_gch  * 8;
    const bf16* vp2 = Vt + vbase  + (size_t)src_row2 * MROWS + src_gch2 * 8;
    bf16* kl1 = &KV[0][0][src_row  * 64 + src_ch  * 8];
    bf16* kl2 = &KV[0][0][src_row2 * 64 + src_ch2 * 8];
    bf16* vl1 = &KV[0][1][src_row  * 64 + src_ch  * 8];
    bf16* vl2 = &KV[0][1][src_row2 * 64 + src_ch2 * 8];
    const ptrdiff_t kstep = 64 * HDIM, vstep = 64;
    const ptrdiff_t lstep = 2 * 64 * 64;

    gload_lds16(kp1, kl1); gload_lds16(kp2, kl2);
    gload_lds16(vp1, vl1); gload_lds16(vp2, vl2);
    __syncthreads();

    bf16x8_t qf[2][2];
    {
        const bf16* Qst = &KV[1][0][0];
        #pragma unroll
        for (int q16 = 0; q16 < 2; ++q16) {
            int row = wq + q16 * 16 + lr;
            #pragma unroll
            for (int ks = 0; ks < 2; ++ks) {
                int ch = (ks * 4 + quad) ^ (row & 7);
                qf[q16][ks] = *reinterpret_cast<const bf16x8_t*>(&Qst[row * 64 + ch * 8]);
            }
        }
    }
    __syncthreads();

    f32x4_t oacc[2][4] = {};
    f32x4_t rsacc[2] = {};
    bf16x4_t ones4;
    ones4[0] = (bf16)1.0f; ones4[1] = (bf16)1.0f; ones4[2] = (bf16)1.0f; ones4[3] = (bf16)1.0f;

    for (int it = 0; it < SEQ / 64; ++it) {
        const int buf = it & 1;
        if (it + 1 < SEQ / 64) {
            const ptrdiff_t g = (ptrdiff_t)(it + 1);
            const ptrdiff_t l = (buf ^ 1) ? lstep : 0;
            gload_lds16(kp1 + g * kstep, kl1 + l); gload_lds16(kp2 + g * kstep, kl2 + l);
            gload_lds16(vp1 + g * vstep, vl1 + l); gload_lds16(vp2 + g * vstep, vl2 + l);
        }

        const bf16* Ks = &KV[buf][0][0];
        const bf16* Vs = &KV[buf][1][0];

        f32x4_t sacc[4][2] = {};
        #pragma unroll
        for (int ks = 0; ks < 2; ++ks) {
            bf16x8_t af[4];
            #pragma unroll
            for (int kt = 0; kt < 4; ++kt) {
                int row = kt * 16 + lr;
                int ch = (ks * 4 + quad) ^ (row & 7);
                af[kt] = *reinterpret_cast<const bf16x8_t*>(&Ks[row * 64 + ch * 8]);
            }
            #pragma unroll
            for (int kt = 0; kt < 4; ++kt)
                #pragma unroll
                for (int q16 = 0; q16 < 2; ++q16)
                    sacc[kt][q16] = __builtin_amdgcn_mfma_f32_16x16x32_bf16(
                        af[kt], qf[q16][ks], sacc[kt][q16], 0, 0, 0);
        }

        #pragma unroll
        for (int kt = 0; kt < 4; ++kt) {
            bf16x4_t bv[4];
            #pragma unroll
            for (int dt = 0; dt < 4; ++dt) {
                int row = dt * 16 + lr;
                int ch = (2 * kt + (quad >> 1)) ^ (row & 7);
                bv[dt] = *reinterpret_cast<const bf16x4_t*>(&Vs[row * 64 + ch * 8 + (quad & 1) * 4]);
            }
            #pragma unroll
            for (int q16 = 0; q16 < 2; ++q16) {
                bf16x4_t pk;
                #pragma unroll
                for (int r = 0; r < 4; ++r)
                    pk[r] = (bf16)__builtin_amdgcn_exp2f(sacc[kt][q16][r]);
                rsacc[q16] = mfma16x16x16bf16(pk, ones4, rsacc[q16]);
                #pragma unroll
                for (int dt = 0; dt < 4; ++dt)
                    oacc[q16][dt] = mfma16x16x16bf16(pk, bv[dt], oacc[q16][dt]);
            }
        }
        __syncthreads();
    }

    #pragma unroll
    for (int q16 = 0; q16 < 2; ++q16) {
        float inv[4];
        #pragma unroll
        for (int r = 0; r < 4; ++r)
            inv[r] = 1.0f / rsacc[q16][r];
        #pragma unroll
        for (int dt = 0; dt < 4; ++dt) {
            #pragma unroll
            for (int r = 0; r < 4; ++r) {
                int q = q0 + wq + q16 * 16 + quad * 4 + r;
                Ab[((size_t)b * SEQ + q) * DIM + h * HDIM + dt * 16 + lr] =
                    (bf16)(oacc[q16][dt][r] * inv[r]);
            }
        }
    }
}

extern "C" void kernel_launch(void* const* d_in, const int* in_sizes, int n_in,
                              void* d_out, int out_size, void* d_ws, size_t ws_size,
                              hipStream_t stream) {
    (void)in_sizes; (void)n_in; (void)out_size; (void)ws_size;
    const float* x  = (const float*)d_in[0];
    const float* Wq = (const float*)d_in[1];
    const float* Wk = (const float*)d_in[2];
    const float* Wv = (const float*)d_in[3];
    const float* Wp = (const float*)d_in[4];
    const float* bp = (const float*)d_in[5];
    float* out = (float*)d_out;

    char* ws = (char*)d_ws;
    size_t off = 0;
    auto alloc = [&](size_t bytes) {
        void* p = ws + off;
        off += (bytes + 255) & ~(size_t)255;
        return p;
    };
    const size_t big = (size_t)MROWS * DIM * sizeof(bf16);
    const size_t wsz = (size_t)DIM * DIM * sizeof(bf16);
    bf16* Xb  = (bf16*)alloc(big);
    bf16* Qb  = (bf16*)alloc(big);
    bf16* Kb  = (bf16*)alloc(big);
    bf16* Vtb = (bf16*)alloc(big);
    bf16* Wqb = (bf16*)alloc(wsz);
    bf16* Wkb = (bf16*)alloc(wsz);
    bf16* Wvb = (bf16*)alloc(wsz);
    bf16* Wpb = (bf16*)alloc(wsz);
    bf16* Ab  = Xb;   // Xb dead after projections

    const int x4 = MROWS * DIM / 4;
    cast_bf16_kernel<<<(x4 + 255) / 256, 256, 0, stream>>>(x, Xb, x4);
    const int w4 = DIM * DIM / 4;
    cast_w4_kernel<<<dim3((w4 + 255) / 256, 4), 256, 0, stream>>>(
        Wq, Wk, Wv, Wp, Wqb, Wkb, Wvb, Wpb, w4);

    qkvv_gemm<<<dim3(DIM / 128, MROWS / 128, 3), 256, 0, stream>>>(
        Xb, Wqb, Wkb, Wvb, Qb, Kb, Vtb);

    attn_kernel<<<dim3(SEQ / 128, BATCH * HEADS), 256, 0, stream>>>(Qb, Kb, Vtb, Ab);

    out_gemm<<<dim3(DIM / 128, MROWS / 64), 256, 0, stream>>>(Ab, Wpb, bp, out);
}

// Round 8
// 224.375 us; speedup vs baseline: 1.0764x; 1.0143x over previous
//
#include <hip/hip_runtime.h>
#include <cstdint>

#define DIM   768
#define HEADS 12
#define HDIM  64
#define BATCH 4
#define SEQ   2048
#define MROWS (BATCH*SEQ)   // 8192

typedef __bf16 bf16;
typedef __bf16 bf16x4_t __attribute__((ext_vector_type(4)));
typedef __bf16 bf16x8_t __attribute__((ext_vector_type(8)));
typedef float  f32x4_t  __attribute__((ext_vector_type(4)));
typedef float  f32x16_t __attribute__((ext_vector_type(16)));

// ---------------- fp32 -> bf16 casts ----------------
__global__ void cast_bf16_kernel(const float* __restrict__ src, bf16* __restrict__ dst, int n4) {
    int i = blockIdx.x * blockDim.x + threadIdx.x;
    if (i >= n4) return;
    const float4 v = reinterpret_cast<const float4*>(src)[i];
    bf16x4_t o;
    o[0] = (bf16)v.x; o[1] = (bf16)v.y; o[2] = (bf16)v.z; o[3] = (bf16)v.w;
    reinterpret_cast<bf16x4_t*>(dst)[i] = o;
}

__global__ void cast_w4_kernel(const float* __restrict__ s0, const float* __restrict__ s1,
                               const float* __restrict__ s2, const float* __restrict__ s3,
                               bf16* __restrict__ d0, bf16* __restrict__ d1,
                               bf16* __restrict__ d2, bf16* __restrict__ d3, int n4) {
    int i = blockIdx.x * blockDim.x + threadIdx.x;
    if (i >= n4) return;
    int y = blockIdx.y;
    const float* src = (y == 0) ? s0 : (y == 1) ? s1 : (y == 2) ? s2 : s3;
    bf16* dst        = (y == 0) ? d0 : (y == 1) ? d1 : (y == 2) ? d2 : d3;
    const float4 v = reinterpret_cast<const float4*>(src)[i];
    bf16x4_t o;
    o[0] = (bf16)v.x; o[1] = (bf16)v.y; o[2] = (bf16)v.z; o[3] = (bf16)v.w;
    reinterpret_cast<bf16x4_t*>(dst)[i] = o;
}

// async global->LDS, 16B per lane. LDS dest is wave-uniform base + lane*16.
__device__ __forceinline__ void gload_lds16(const bf16* g, bf16* l) {
    __builtin_amdgcn_global_load_lds((const __attribute__((address_space(1))) void*)g,
                                     (__attribute__((address_space(3))) void*)l, 16, 0, 0);
}

// ---------------- merged projection GEMM ----------------
// z=0 -> Q [B,H,N,64] (pre-scaled by log2(e)/8): A=X(m=sample), B=Wq(n=dfull)
// z=1 -> K [B,H,N,64]:                            A=X,          B=Wk
// z=2 -> Vt [768][8192]:                          A=Wv(m=dfull), B=X(n=sample)
__global__ __launch_bounds__(256, 3) void qkvv_gemm(
        const bf16* __restrict__ X,
        const bf16* __restrict__ Wq, const bf16* __restrict__ Wk, const bf16* __restrict__ Wv,
        bf16* __restrict__ Q, bf16* __restrict__ Kd, bf16* __restrict__ Vt)
{
    __shared__ bf16 As[128*32];
    __shared__ bf16 Bs[128*32];
    const int tid  = threadIdx.x;
    const int z    = blockIdx.z;
    const bf16* Ap; const bf16* Bp;
    int m0, n0;
    if (z == 2) { Ap = Wv; Bp = X;               m0 = blockIdx.x * 128; n0 = blockIdx.y * 128; }
    else        { Ap = X;  Bp = (z ? Wk : Wq);   m0 = blockIdx.y * 128; n0 = blockIdx.x * 128; }
    const int lane = tid & 63;
    const int w    = tid >> 6;
    const int wm   = (w & 1) * 64, wn = (w >> 1) * 64;
    const int lr   = lane & 15, quad = lane >> 4;

    f32x4_t acc[4][4] = {};

    for (int kk = 0; kk < DIM; kk += 32) {
        #pragma unroll
        for (int i = 0; i < 2; ++i) {
            int c = tid + i * 256;
            int row = c >> 2, ko = (c & 3) * 8;
            gload_lds16(Ap + (size_t)(m0 + row) * DIM + kk + ko, &As[row * 32 + ko]);
            gload_lds16(Bp + (size_t)(n0 + row) * DIM + kk + ko, &Bs[row * 32 + ko]);
        }
        __syncthreads();
        bf16x8_t af[4], bfr[4];
        #pragma unroll
        for (int i = 0; i < 4; ++i)
            af[i] = *reinterpret_cast<const bf16x8_t*>(&As[(wm + i * 16 + lr) * 32 + quad * 8]);
        #pragma unroll
        for (int j = 0; j < 4; ++j)
            bfr[j] = *reinterpret_cast<const bf16x8_t*>(&Bs[(wn + j * 16 + lr) * 32 + quad * 8]);
        #pragma unroll
        for (int i = 0; i < 4; ++i)
            #pragma unroll
            for (int j = 0; j < 4; ++j)
                acc[i][j] = __builtin_amdgcn_mfma_f32_16x16x32_bf16(af[i], bfr[j], acc[i][j], 0, 0, 0);
        __syncthreads();
    }

    if (z == 2) {
        #pragma unroll
        for (int i = 0; i < 4; ++i) {
            int mbase = m0 + wm + i * 16 + quad * 4;
            #pragma unroll
            for (int j = 0; j < 4; ++j) {
                int n = n0 + wn + j * 16 + lr;
                #pragma unroll
                for (int r = 0; r < 4; ++r)
                    Vt[(size_t)(mbase + r) * MROWS + n] = (bf16)acc[i][j][r];
            }
        }
    } else {
        const float sc = (z == 0) ? 0.18033688011112042f : 1.0f;  // log2(e)/8 folded into Q
        bf16* dst = (z == 0) ? Q : Kd;
        #pragma unroll
        for (int i = 0; i < 4; ++i) {
            int mbase = m0 + wm + i * 16 + quad * 4;
            #pragma unroll
            for (int j = 0; j < 4; ++j) {
                int n = n0 + wn + j * 16 + lr;
                int h = n >> 6, d = n & 63;
                #pragma unroll
                for (int r = 0; r < 4; ++r) {
                    int m = mbase + r;
                    int b = m >> 11, row = m & 2047;
                    dst[(((size_t)b * HEADS + h) * SEQ + row) * HDIM + d] = (bf16)(acc[i][j][r] * sc);
                }
            }
        }
    }
}

// ---------------- output projection GEMM (+bias, fp32 out) ----------------
__global__ __launch_bounds__(256, 4) void out_gemm(
        const bf16* __restrict__ A,       // [8192,768]
        const bf16* __restrict__ W,       // [768,768]
        const float* __restrict__ bias,
        float* __restrict__ out)          // [8192,768] f32
{
    __shared__ bf16 As[64*32];
    __shared__ bf16 Bs[128*32];
    const int tid  = threadIdx.x;
    const int n0   = blockIdx.x * 128;
    const int m0   = blockIdx.y * 64;
    const int lane = tid & 63;
    const int w    = tid >> 6;
    const int wm   = (w & 1) * 32, wn = (w >> 1) * 64;
    const int lr   = lane & 15, quad = lane >> 4;

    f32x4_t acc[2][4] = {};

    for (int kk = 0; kk < DIM; kk += 32) {
        {
            int row = tid >> 2, ko = (tid & 3) * 8;
            gload_lds16(A + (size_t)(m0 + row) * DIM + kk + ko, &As[row * 32 + ko]);
        }
        #pragma unroll
        for (int i = 0; i < 2; ++i) {
            int c = tid + i * 256;
            int row = c >> 2, ko = (c & 3) * 8;
            gload_lds16(W + (size_t)(n0 + row) * DIM + kk + ko, &Bs[row * 32 + ko]);
        }
        __syncthreads();
        bf16x8_t af[2], bfr[4];
        #pragma unroll
        for (int i = 0; i < 2; ++i)
            af[i] = *reinterpret_cast<const bf16x8_t*>(&As[(wm + i * 16 + lr) * 32 + quad * 8]);
        #pragma unroll
        for (int j = 0; j < 4; ++j)
            bfr[j] = *reinterpret_cast<const bf16x8_t*>(&Bs[(wn + j * 16 + lr) * 32 + quad * 8]);
        #pragma unroll
        for (int i = 0; i < 2; ++i)
            #pragma unroll
            for (int j = 0; j < 4; ++j)
                acc[i][j] = __builtin_amdgcn_mfma_f32_16x16x32_bf16(af[i], bfr[j], acc[i][j], 0, 0, 0);
        __syncthreads();
    }

    #pragma unroll
    for (int i = 0; i < 2; ++i) {
        int mbase = m0 + wm + i * 16 + quad * 4;
        #pragma unroll
        for (int j = 0; j < 4; ++j) {
            int n = n0 + wn + j * 16 + lr;
            float bv = bias[n];
            #pragma unroll
            for (int r = 0; r < 4; ++r) {
                int m = mbase + r;
                out[(size_t)m * DIM + n] = acc[i][j][r] + bv;
            }
        }
    }
}

// ---------------- flash attention v6: 32x32 MFMAs ----------------
// Wave owns 32 queries (Q-tile 128). S^T (M=key32, N=query32) via 32x32x16;
// its C-layout is directly the A-operand of the PV 32x32x16 under a consistent
// k-slot permutation kappa(hw,j)=(j&3)+8*(j>>2)+4*hw (+16*kg). V B-frags are
// read from LDS in that permuted key order (2x ds_read_b64). Rowsum via
// ones-B MFMA -> same C-layout as oacc. 20 MFMAs/iter vs 56 before.
__global__ __launch_bounds__(256, 3) void attn_kernel(
        const bf16* __restrict__ Q, const bf16* __restrict__ Kd,
        const bf16* __restrict__ Vt, bf16* __restrict__ Ab)
{
    __shared__ __align__(16) bf16 KV[2][2][64*64];   // [buf][K|V][row*64] swizzled

    const int tid  = threadIdx.x;
    const int bh   = blockIdx.y;
    const int b    = bh / HEADS, h = bh % HEADS;
    const int q0   = blockIdx.x * 128;
    const int lane = tid & 63, w = tid >> 6;
    const int l31  = lane & 31, hw = lane >> 5;
    const int wq   = w * 32;

    const size_t qkbase = (size_t)bh * SEQ * HDIM;
    const size_t vbase  = (size_t)h * HDIM * MROWS + (size_t)b * SEQ;

    const int src_row = tid >> 3, src_ch = tid & 7;
    const int src_gch = src_ch ^ (src_row & 7);
    const int src_row2 = (tid + 256) >> 3, src_ch2 = tid & 7;
    const int src_gch2 = src_ch2 ^ (src_row2 & 7);

    // stage Q (128x64, swizzled) into KV[1] (16 KB)
    {
        bf16* Qst = &KV[1][0][0];
        #pragma unroll
        for (int i = 0; i < 4; ++i) {
            int c = tid + i * 256;
            int row = c >> 3, ch = c & 7;
            int gch = ch ^ (row & 7);
            gload_lds16(Q + qkbase + (size_t)(q0 + row) * HDIM + gch * 8, &Qst[row * 64 + ch * 8]);
        }
    }

    const bf16* kp1 = Kd + qkbase + (size_t)src_row  * HDIM + src_gch  * 8;
    const bf16* kp2 = Kd + qkbase + (size_t)src_row2 * HDIM + src_gch2 * 8;
    const bf16* vp1 = Vt + vbase  + (size_t)src_row  * MROWS + src_gch  * 8;
    const bf16* vp2 = Vt + vbase  + (size_t)src_row2 * MROWS + src_gch2 * 8;
    bf16* kl1 = &KV[0][0][src_row  * 64 + src_ch  * 8];
    bf16* kl2 = &KV[0][0][src_row2 * 64 + src_ch2 * 8];
    bf16* vl1 = &KV[0][1][src_row  * 64 + src_ch  * 8];
    bf16* vl2 = &KV[0][1][src_row2 * 64 + src_ch2 * 8];
    const ptrdiff_t kstep = 64 * HDIM, vstep = 64;
    const ptrdiff_t lstep = 2 * 64 * 64;

    gload_lds16(kp1, kl1); gload_lds16(kp2, kl2);
    gload_lds16(vp1, vl1); gload_lds16(vp2, vl2);
    __syncthreads();

    // Q B-operand frags: qf[g] = Q[wq+l31][dims g*16+8*hw .. +7]
    bf16x8_t qf[4];
    {
        const bf16* Qst = &KV[1][0][0];
        int row = wq + l31;
        #pragma unroll
        for (int g = 0; g < 4; ++g) {
            int ch = (2 * g + hw) ^ (row & 7);
            qf[g] = *reinterpret_cast<const bf16x8_t*>(&Qst[row * 64 + ch * 8]);
        }
    }
    __syncthreads();   // KV[1] becomes buf 1

    f32x16_t oacc[2] = {};   // [d-chunk]: col=d, row=query
    f32x16_t rsacc  = {};    // same layout (col ignored)
    bf16x8_t ones8;
    #pragma unroll
    for (int i = 0; i < 8; ++i) ones8[i] = (bf16)1.0f;

    for (int it = 0; it < SEQ / 64; ++it) {
        const int buf = it & 1;
        if (it + 1 < SEQ / 64) {
            const ptrdiff_t g = (ptrdiff_t)(it + 1);
            const ptrdiff_t l = (buf ^ 1) ? lstep : 0;
            gload_lds16(kp1 + g * kstep, kl1 + l); gload_lds16(kp2 + g * kstep, kl2 + l);
            gload_lds16(vp1 + g * vstep, vl1 + l); gload_lds16(vp2 + g * vstep, vl2 + l);
        }

        const bf16* Ks = &KV[buf][0][0];
        const bf16* Vs = &KV[buf][1][0];

        // S^T: sacc[kc] over keys kc*32..+31, queries wq..wq+31
        f32x16_t sacc[2] = {};
        #pragma unroll
        for (int kc = 0; kc < 2; ++kc) {
            int row = kc * 32 + l31;
            #pragma unroll
            for (int g = 0; g < 4; ++g) {
                int ch = (2 * g + hw) ^ (row & 7);
                bf16x8_t af = *reinterpret_cast<const bf16x8_t*>(&Ks[row * 64 + ch * 8]);
                sacc[kc] = __builtin_amdgcn_mfma_f32_32x32x16_bf16(af, qf[g], sacc[kc], 0, 0, 0);
            }
        }

        // p = exp2(s); pk[kg] = regs (kg&1)*8..+7 of sacc[kg>>1]
        bf16x8_t pk[4];
        #pragma unroll
        for (int kg = 0; kg < 4; ++kg) {
            #pragma unroll
            for (int j = 0; j < 8; ++j)
                pk[kg][j] = (bf16)__builtin_amdgcn_exp2f(sacc[kg >> 1][(kg & 1) * 8 + j]);
        }

        // rowsum: ones-B -> same C layout as oacc
        #pragma unroll
        for (int kg = 0; kg < 4; ++kg)
            rsacc = __builtin_amdgcn_mfma_f32_32x32x16_bf16(pk[kg], ones8, rsacc, 0, 0, 0);

        // PV: B-frag slot (hw,j) = key kappa(hw,j)+16*kg at column d
        #pragma unroll
        for (int dc = 0; dc < 2; ++dc) {
            int row = dc * 32 + l31;            // Vs row = d
            #pragma unroll
            for (int kg = 0; kg < 4; ++kg) {
                int ch1 = (2 * kg)     ^ (row & 7);
                int ch2 = (2 * kg + 1) ^ (row & 7);
                bf16x4_t lo = *reinterpret_cast<const bf16x4_t*>(&Vs[row * 64 + ch1 * 8 + hw * 4]);
                bf16x4_t hi = *reinterpret_cast<const bf16x4_t*>(&Vs[row * 64 + ch2 * 8 + hw * 4]);
                bf16x8_t bb;
                bb[0]=lo[0]; bb[1]=lo[1]; bb[2]=lo[2]; bb[3]=lo[3];
                bb[4]=hi[0]; bb[5]=hi[1]; bb[6]=hi[2]; bb[7]=hi[3];
                oacc[dc] = __builtin_amdgcn_mfma_f32_32x32x16_bf16(pk[kg], bb, oacc[dc], 0, 0, 0);
            }
        }
        __syncthreads();
    }

    // normalize + store: lane holds d = dc*32+l31; reg -> query (reg&3)+8*(reg>>2)+4*hw
    float inv[16];
    #pragma unroll
    for (int r = 0; r < 16; ++r)
        inv[r] = 1.0f / rsacc[r];
    #pragma unroll
    for (int dc = 0; dc < 2; ++dc) {
        int d = dc * 32 + l31;
        #pragma unroll
        for (int r = 0; r < 16; ++r) {
            int q = q0 + wq + (r & 3) + 8 * (r >> 2) + 4 * hw;
            Ab[((size_t)b * SEQ + q) * DIM + h * HDIM + d] = (bf16)(oacc[dc][r] * inv[r]);
        }
    }
}

extern "C" void kernel_launch(void* const* d_in, const int* in_sizes, int n_in,
                              void* d_out, int out_size, void* d_ws, size_t ws_size,
                              hipStream_t stream) {
    (void)in_sizes; (void)n_in; (void)out_size; (void)ws_size;
    const float* x  = (const float*)d_in[0];
    const float* Wq = (const float*)d_in[1];
    const float* Wk = (const float*)d_in[2];
    const float* Wv = (const float*)d_in[3];
    const float* Wp = (const float*)d_in[4];
    const float* bp = (const float*)d_in[5];
    float* out = (float*)d_out;

    char* ws = (char*)d_ws;
    size_t off = 0;
    auto alloc = [&](size_t bytes) {
        void* p = ws + off;
        off += (bytes + 255) & ~(size_t)255;
        return p;
    };
    const size_t big = (size_t)MROWS * DIM * sizeof(bf16);
    const size_t wsz = (size_t)DIM * DIM * sizeof(bf16);
    bf16* Xb  = (bf16*)alloc(big);
    bf16* Qb  = (bf16*)alloc(big);
    bf16* Kb  = (bf16*)alloc(big);
    bf16* Vtb = (bf16*)alloc(big);
    bf16* Wqb = (bf16*)alloc(wsz);
    bf16* Wkb = (bf16*)alloc(wsz);
    bf16* Wvb = (bf16*)alloc(wsz);
    bf16* Wpb = (bf16*)alloc(wsz);
    bf16* Ab  = Xb;   // Xb dead after projections

    const int x4 = MROWS * DIM / 4;
    cast_bf16_kernel<<<(x4 + 255) / 256, 256, 0, stream>>>(x, Xb, x4);
    const int w4 = DIM * DIM / 4;
    cast_w4_kernel<<<dim3((w4 + 255) / 256, 4), 256, 0, stream>>>(
        Wq, Wk, Wv, Wp, Wqb, Wkb, Wvb, Wpb, w4);

    qkvv_gemm<<<dim3(DIM / 128, MROWS / 128, 3), 256, 0, stream>>>(
        Xb, Wqb, Wkb, Wvb, Qb, Kb, Vtb);

    attn_kernel<<<dim3(SEQ / 128, BATCH * HEADS), 256, 0, stream>>>(Qb, Kb, Vtb, Ab);

    out_gemm<<<dim3(DIM / 128, MROWS / 64), 256, 0, stream>>>(Ab, Wpb, bp, out);
}

// Round 9
// 218.704 us; speedup vs baseline: 1.1044x; 1.0259x over previous
//
#include <hip/hip_runtime.h>
#include <cstdint>

#define DIM   768
#define HEADS 12
#define HDIM  64
#define BATCH 4
#define SEQ   2048
#define MROWS (BATCH*SEQ)   // 8192

typedef __bf16 bf16;
typedef __bf16 bf16x4_t __attribute__((ext_vector_type(4)));
typedef __bf16 bf16x8_t __attribute__((ext_vector_type(8)));
typedef float  f32x4_t  __attribute__((ext_vector_type(4)));
typedef float  f32x16_t __attribute__((ext_vector_type(16)));

// ---------------- fp32 -> bf16 casts ----------------
__global__ void cast_bf16_kernel(const float* __restrict__ src, bf16* __restrict__ dst, int n4) {
    int i = blockIdx.x * blockDim.x + threadIdx.x;
    if (i >= n4) return;
    const float4 v = reinterpret_cast<const float4*>(src)[i];
    bf16x4_t o;
    o[0] = (bf16)v.x; o[1] = (bf16)v.y; o[2] = (bf16)v.z; o[3] = (bf16)v.w;
    reinterpret_cast<bf16x4_t*>(dst)[i] = o;
}

__global__ void cast_w4_kernel(const float* __restrict__ s0, const float* __restrict__ s1,
                               const float* __restrict__ s2, const float* __restrict__ s3,
                               bf16* __restrict__ d0, bf16* __restrict__ d1,
                               bf16* __restrict__ d2, bf16* __restrict__ d3, int n4) {
    int i = blockIdx.x * blockDim.x + threadIdx.x;
    if (i >= n4) return;
    int y = blockIdx.y;
    const float* src = (y == 0) ? s0 : (y == 1) ? s1 : (y == 2) ? s2 : s3;
    bf16* dst        = (y == 0) ? d0 : (y == 1) ? d1 : (y == 2) ? d2 : d3;
    const float4 v = reinterpret_cast<const float4*>(src)[i];
    bf16x4_t o;
    o[0] = (bf16)v.x; o[1] = (bf16)v.y; o[2] = (bf16)v.z; o[3] = (bf16)v.w;
    reinterpret_cast<bf16x4_t*>(dst)[i] = o;
}

// async global->LDS, 16B per lane. LDS dest is wave-uniform base + lane*16.
__device__ __forceinline__ void gload_lds16(const bf16* g, bf16* l) {
    __builtin_amdgcn_global_load_lds((const __attribute__((address_space(1))) void*)g,
                                     (__attribute__((address_space(3))) void*)l, 16, 0, 0);
}

// ---------------- merged projection GEMM v2 ----------------
// All slices: A = W{q,k,v} (M=dfull), B = X (N=sample) -> C[dfull][sample].
// BK=64, XOR chunk swizzle (2-way = free), 128x128 tile.
// z=0 -> Q [B,H,N,64] (pre-scaled by log2(e)/8), packed bf16x4 stores
// z=1 -> K [B,H,N,64], packed bf16x4 stores
// z=2 -> Vt [768][8192] row-major
__global__ __launch_bounds__(256, 3) void qkvv_gemm(
        const bf16* __restrict__ X,
        const bf16* __restrict__ Wq, const bf16* __restrict__ Wk, const bf16* __restrict__ Wv,
        bf16* __restrict__ Q, bf16* __restrict__ Kd, bf16* __restrict__ Vt)
{
    __shared__ __align__(16) bf16 As[128*64];   // W rows (dfull), swizzled
    __shared__ __align__(16) bf16 Bs[128*64];   // X rows (sample), swizzled
    const int tid  = threadIdx.x;
    const int z    = blockIdx.z;
    const bf16* Ap = (z == 0) ? Wq : (z == 1 ? Wk : Wv);
    const int m0   = blockIdx.x * 128;   // dfull
    const int n0   = blockIdx.y * 128;   // sample
    const int lane = tid & 63;
    const int w    = tid >> 6;
    const int wm   = (w & 1) * 64, wn = (w >> 1) * 64;
    const int lr   = lane & 15, quad = lane >> 4;

    f32x4_t acc[4][4] = {};

    for (int kk = 0; kk < DIM; kk += 64) {
        #pragma unroll
        for (int i = 0; i < 4; ++i) {
            int c = tid + i * 256;              // 0..1023
            int row = c >> 3, ch = c & 7;
            int gch = ch ^ (row & 7);
            gload_lds16(Ap + (size_t)(m0 + row) * DIM + kk + gch * 8, &As[row * 64 + ch * 8]);
            gload_lds16(X  + (size_t)(n0 + row) * DIM + kk + gch * 8, &Bs[row * 64 + ch * 8]);
        }
        __syncthreads();
        #pragma unroll
        for (int ks = 0; ks < 2; ++ks) {
            bf16x8_t af[4], bfr[4];
            #pragma unroll
            for (int i = 0; i < 4; ++i) {
                int row = wm + i * 16 + lr;
                int ch = (ks * 4 + quad) ^ (row & 7);
                af[i] = *reinterpret_cast<const bf16x8_t*>(&As[row * 64 + ch * 8]);
            }
            #pragma unroll
            for (int j = 0; j < 4; ++j) {
                int row = wn + j * 16 + lr;
                int ch = (ks * 4 + quad) ^ (row & 7);
                bfr[j] = *reinterpret_cast<const bf16x8_t*>(&Bs[row * 64 + ch * 8]);
            }
            #pragma unroll
            for (int i = 0; i < 4; ++i)
                #pragma unroll
                for (int j = 0; j < 4; ++j)
                    acc[i][j] = __builtin_amdgcn_mfma_f32_16x16x32_bf16(af[i], bfr[j], acc[i][j], 0, 0, 0);
        }
        __syncthreads();
    }

    if (z == 2) {
        // Vt[dfull][sample]; sample = n+lr is coalesced (2B x16 = 32B segments)
        #pragma unroll
        for (int i = 0; i < 4; ++i) {
            int mbase = m0 + wm + i * 16 + quad * 4;
            #pragma unroll
            for (int j = 0; j < 4; ++j) {
                int n = n0 + wn + j * 16 + lr;
                #pragma unroll
                for (int r = 0; r < 4; ++r)
                    Vt[(size_t)(mbase + r) * MROWS + n] = (bf16)acc[i][j][r];
            }
        }
    } else {
        // lane's 4 regs = 4 consecutive dfull -> packed bf16x4 store
        const float sc = (z == 0) ? 0.18033688011112042f : 1.0f;   // log2(e)/8 into Q
        bf16* dst = (z == 0) ? Q : Kd;
        #pragma unroll
        for (int i = 0; i < 4; ++i) {
            int mb = m0 + wm + i * 16 + quad * 4;   // dfull base, mult of 4
            int h  = mb >> 6, d0 = mb & 63;
            #pragma unroll
            for (int j = 0; j < 4; ++j) {
                int sample = n0 + wn + j * 16 + lr;
                int b = sample >> 11, srow = sample & 2047;
                bf16x4_t o;
                #pragma unroll
                for (int r = 0; r < 4; ++r)
                    o[r] = (bf16)(acc[i][j][r] * sc);
                *reinterpret_cast<bf16x4_t*>(
                    &dst[(((size_t)b * HEADS + h) * SEQ + srow) * HDIM + d0]) = o;
            }
        }
    }
}

// ---------------- output projection GEMM (+bias, fp32 out) ----------------
// 64x128 tile, BK=64, swizzled. grid (6,128)=768 blocks = 3-4/CU balanced.
__global__ __launch_bounds__(256, 4) void out_gemm(
        const bf16* __restrict__ A,       // [8192,768]
        const bf16* __restrict__ W,       // [768,768]
        const float* __restrict__ bias,
        float* __restrict__ out)          // [8192,768] f32
{
    __shared__ __align__(16) bf16 As[64*64];
    __shared__ __align__(16) bf16 Bs[128*64];
    const int tid  = threadIdx.x;
    const int n0   = blockIdx.x * 128;
    const int m0   = blockIdx.y * 64;
    const int lane = tid & 63;
    const int w    = tid >> 6;
    const int wm   = (w & 1) * 32, wn = (w >> 1) * 64;
    const int lr   = lane & 15, quad = lane >> 4;

    f32x4_t acc[2][4] = {};

    for (int kk = 0; kk < DIM; kk += 64) {
        #pragma unroll
        for (int i = 0; i < 2; ++i) {           // As: 64x64 = 512 chunks
            int c = tid + i * 256;
            int row = c >> 3, ch = c & 7;
            int gch = ch ^ (row & 7);
            gload_lds16(A + (size_t)(m0 + row) * DIM + kk + gch * 8, &As[row * 64 + ch * 8]);
        }
        #pragma unroll
        for (int i = 0; i < 4; ++i) {           // Bs: 128x64 = 1024 chunks
            int c = tid + i * 256;
            int row = c >> 3, ch = c & 7;
            int gch = ch ^ (row & 7);
            gload_lds16(W + (size_t)(n0 + row) * DIM + kk + gch * 8, &Bs[row * 64 + ch * 8]);
        }
        __syncthreads();
        #pragma unroll
        for (int ks = 0; ks < 2; ++ks) {
            bf16x8_t af[2], bfr[4];
            #pragma unroll
            for (int i = 0; i < 2; ++i) {
                int row = wm + i * 16 + lr;
                int ch = (ks * 4 + quad) ^ (row & 7);
                af[i] = *reinterpret_cast<const bf16x8_t*>(&As[row * 64 + ch * 8]);
            }
            #pragma unroll
            for (int j = 0; j < 4; ++j) {
                int row = wn + j * 16 + lr;
                int ch = (ks * 4 + quad) ^ (row & 7);
                bfr[j] = *reinterpret_cast<const bf16x8_t*>(&Bs[row * 64 + ch * 8]);
            }
            #pragma unroll
            for (int i = 0; i < 2; ++i)
                #pragma unroll
                for (int j = 0; j < 4; ++j)
                    acc[i][j] = __builtin_amdgcn_mfma_f32_16x16x32_bf16(af[i], bfr[j], acc[i][j], 0, 0, 0);
        }
        __syncthreads();
    }

    #pragma unroll
    for (int i = 0; i < 2; ++i) {
        int mbase = m0 + wm + i * 16 + quad * 4;
        #pragma unroll
        for (int j = 0; j < 4; ++j) {
            int n = n0 + wn + j * 16 + lr;
            float bv = bias[n];
            #pragma unroll
            for (int r = 0; r < 4; ++r) {
                int m = mbase + r;
                out[(size_t)m * DIM + n] = acc[i][j][r] + bv;
            }
        }
    }
}

// ---------------- flash attention v6 (round-8, unchanged) ----------------
__global__ __launch_bounds__(256, 3) void attn_kernel(
        const bf16* __restrict__ Q, const bf16* __restrict__ Kd,
        const bf16* __restrict__ Vt, bf16* __restrict__ Ab)
{
    __shared__ __align__(16) bf16 KV[2][2][64*64];   // [buf][K|V][row*64] swizzled

    const int tid  = threadIdx.x;
    const int bh   = blockIdx.y;
    const int b    = bh / HEADS, h = bh % HEADS;
    const int q0   = blockIdx.x * 128;
    const int lane = tid & 63, w = tid >> 6;
    const int l31  = lane & 31, hw = lane >> 5;
    const int wq   = w * 32;

    const size_t qkbase = (size_t)bh * SEQ * HDIM;
    const size_t vbase  = (size_t)h * HDIM * MROWS + (size_t)b * SEQ;

    const int src_row = tid >> 3, src_ch = tid & 7;
    const int src_gch = src_ch ^ (src_row & 7);
    const int src_row2 = (tid + 256) >> 3, src_ch2 = tid & 7;
    const int src_gch2 = src_ch2 ^ (src_row2 & 7);

    {
        bf16* Qst = &KV[1][0][0];
        #pragma unroll
        for (int i = 0; i < 4; ++i) {
            int c = tid + i * 256;
            int row = c >> 3, ch = c & 7;
            int gch = ch ^ (row & 7);
            gload_lds16(Q + qkbase + (size_t)(q0 + row) * HDIM + gch * 8, &Qst[row * 64 + ch * 8]);
        }
    }

    const bf16* kp1 = Kd + qkbase + (size_t)src_row  * HDIM + src_gch  * 8;
    const bf16* kp2 = Kd + qkbase + (size_t)src_row2 * HDIM + src_gch2 * 8;
    const bf16* vp1 = Vt + vbase  + (size_t)src_row  * MROWS + src_gch  * 8;
    const bf16* vp2 = Vt + vbase  + (size_t)src_row2 * MROWS + src_gch2 * 8;
    bf16* kl1 = &KV[0][0][src_row  * 64 + src_ch  * 8];
    bf16* kl2 = &KV[0][0][src_row2 * 64 + src_ch2 * 8];
    bf16* vl1 = &KV[0][1][src_row  * 64 + src_ch  * 8];
    bf16* vl2 = &KV[0][1][src_row2 * 64 + src_ch2 * 8];
    const ptrdiff_t kstep = 64 * HDIM, vstep = 64;
    const ptrdiff_t lstep = 2 * 64 * 64;

    gload_lds16(kp1, kl1); gload_lds16(kp2, kl2);
    gload_lds16(vp1, vl1); gload_lds16(vp2, vl2);
    __syncthreads();

    bf16x8_t qf[4];
    {
        const bf16* Qst = &KV[1][0][0];
        int row = wq + l31;
        #pragma unroll
        for (int g = 0; g < 4; ++g) {
            int ch = (2 * g + hw) ^ (row & 7);
            qf[g] = *reinterpret_cast<const bf16x8_t*>(&Qst[row * 64 + ch * 8]);
        }
    }
    __syncthreads();

    f32x16_t oacc[2] = {};
    f32x16_t rsacc  = {};
    bf16x8_t ones8;
    #pragma unroll
    for (int i = 0; i < 8; ++i) ones8[i] = (bf16)1.0f;

    for (int it = 0; it < SEQ / 64; ++it) {
        const int buf = it & 1;
        if (it + 1 < SEQ / 64) {
            const ptrdiff_t g = (ptrdiff_t)(it + 1);
            const ptrdiff_t l = (buf ^ 1) ? lstep : 0;
            gload_lds16(kp1 + g * kstep, kl1 + l); gload_lds16(kp2 + g * kstep, kl2 + l);
            gload_lds16(vp1 + g * vstep, vl1 + l); gload_lds16(vp2 + g * vstep, vl2 + l);
        }

        const bf16* Ks = &KV[buf][0][0];
        const bf16* Vs = &KV[buf][1][0];

        f32x16_t sacc[2] = {};
        #pragma unroll
        for (int kc = 0; kc < 2; ++kc) {
            int row = kc * 32 + l31;
            #pragma unroll
            for (int g = 0; g < 4; ++g) {
                int ch = (2 * g + hw) ^ (row & 7);
                bf16x8_t af = *reinterpret_cast<const bf16x8_t*>(&Ks[row * 64 + ch * 8]);
                sacc[kc] = __builtin_amdgcn_mfma_f32_32x32x16_bf16(af, qf[g], sacc[kc], 0, 0, 0);
            }
        }

        bf16x8_t pk[4];
        #pragma unroll
        for (int kg = 0; kg < 4; ++kg) {
            #pragma unroll
            for (int j = 0; j < 8; ++j)
                pk[kg][j] = (bf16)__builtin_amdgcn_exp2f(sacc[kg >> 1][(kg & 1) * 8 + j]);
        }

        #pragma unroll
        for (int kg = 0; kg < 4; ++kg)
            rsacc = __builtin_amdgcn_mfma_f32_32x32x16_bf16(pk[kg], ones8, rsacc, 0, 0, 0);

        #pragma unroll
        for (int dc = 0; dc < 2; ++dc) {
            int row = dc * 32 + l31;
            #pragma unroll
            for (int kg = 0; kg < 4; ++kg) {
                int ch1 = (2 * kg)     ^ (row & 7);
                int ch2 = (2 * kg + 1) ^ (row & 7);
                bf16x4_t lo = *reinterpret_cast<const bf16x4_t*>(&Vs[row * 64 + ch1 * 8 + hw * 4]);
                bf16x4_t hi = *reinterpret_cast<const bf16x4_t*>(&Vs[row * 64 + ch2 * 8 + hw * 4]);
                bf16x8_t bb;
                bb[0]=lo[0]; bb[1]=lo[1]; bb[2]=lo[2]; bb[3]=lo[3];
                bb[4]=hi[0]; bb[5]=hi[1]; bb[6]=hi[2]; bb[7]=hi[3];
                oacc[dc] = __builtin_amdgcn_mfma_f32_32x32x16_bf16(pk[kg], bb, oacc[dc], 0, 0, 0);
            }
        }
        __syncthreads();
    }

    float inv[16];
    #pragma unroll
    for (int r = 0; r < 16; ++r)
        inv[r] = 1.0f / rsacc[r];
    #pragma unroll
    for (int dc = 0; dc < 2; ++dc) {
        int d = dc * 32 + l31;
        #pragma unroll
        for (int r = 0; r < 16; ++r) {
            int q = q0 + wq + (r & 3) + 8 * (r >> 2) + 4 * hw;
            Ab[((size_t)b * SEQ + q) * DIM + h * HDIM + d] = (bf16)(oacc[dc][r] * inv[r]);
        }
    }
}

extern "C" void kernel_launch(void* const* d_in, const int* in_sizes, int n_in,
                              void* d_out, int out_size, void* d_ws, size_t ws_size,
                              hipStream_t stream) {
    (void)in_sizes; (void)n_in; (void)out_size; (void)ws_size;
    const float* x  = (const float*)d_in[0];
    const float* Wq = (const float*)d_in[1];
    const float* Wk = (const float*)d_in[2];
    const float* Wv = (const float*)d_in[3];
    const float* Wp = (const float*)d_in[4];
    const float* bp = (const float*)d_in[5];
    float* out = (float*)d_out;

    char* ws = (char*)d_ws;
    size_t off = 0;
    auto alloc = [&](size_t bytes) {
        void* p = ws + off;
        off += (bytes + 255) & ~(size_t)255;
        return p;
    };
    const size_t big = (size_t)MROWS * DIM * sizeof(bf16);
    const size_t wsz = (size_t)DIM * DIM * sizeof(bf16);
    bf16* Xb  = (bf16*)alloc(big);
    bf16* Qb  = (bf16*)alloc(big);
    bf16* Kb  = (bf16*)alloc(big);
    bf16* Vtb = (bf16*)alloc(big);
    bf16* Wqb = (bf16*)alloc(wsz);
    bf16* Wkb = (bf16*)alloc(wsz);
    bf16* Wvb = (bf16*)alloc(wsz);
    bf16* Wpb = (bf16*)alloc(wsz);
    bf16* Ab  = Xb;   // Xb dead after projections

    const int x4 = MROWS * DIM / 4;
    cast_bf16_kernel<<<(x4 + 255) / 256, 256, 0, stream>>>(x, Xb, x4);
    const int w4 = DIM * DIM / 4;
    cast_w4_kernel<<<dim3((w4 + 255) / 256, 4), 256, 0, stream>>>(
        Wq, Wk, Wv, Wp, Wqb, Wkb, Wvb, Wpb, w4);

    qkvv_gemm<<<dim3(DIM / 128, MROWS / 128, 3), 256, 0, stream>>>(
        Xb, Wqb, Wkb, Wvb, Qb, Kb, Vtb);

    attn_kernel<<<dim3(SEQ / 128, BATCH * HEADS), 256, 0, stream>>>(Qb, Kb, Vtb, Ab);

    out_gemm<<<dim3(DIM / 128, MROWS / 64), 256, 0, stream>>>(Ab, Wpb, bp, out);
}